// Round 4
// baseline (356.647 us; speedup 1.0000x reference)
//
#include <hip/hip_runtime.h>

#define KK 50000
#define EE 128
#define HH 512
#define DIN 513

typedef short bh8 __attribute__((ext_vector_type(8)));
typedef float fx16 __attribute__((ext_vector_type(16)));

__device__ __forceinline__ short f2b(float f) {
  unsigned u = __float_as_uint(f);
  u = u + 0x7fffu + ((u >> 16) & 1u);
  return (short)(u >> 16);
}
__device__ __forceinline__ float b2f(short b) {
  return __uint_as_float(((unsigned)(unsigned short)b) << 16);
}
__device__ __forceinline__ float sigm(float x) { return 1.f / (1.f + __expf(-x)); }
__device__ __forceinline__ float tanh_(float x) {
  float ax = fabsf(x);
  float e = __expf(-2.f * ax);
  float t = (1.f - e) / (1.f + e);
  return copysignf(t, x);
}

// alpha[r] = dot(km[r,:], o_e) ; 16 lanes per row, 8 f32 each
__global__ void k_alpha(const float* __restrict__ km, const float* __restrict__ oe,
                        float* __restrict__ alpha) {
  int t = blockIdx.x * 256 + threadIdx.x;
  int r = t >> 4, j = t & 15;
  if (r >= KK) return;
  const float4* p = (const float4*)(km + (size_t)r * EE + j * 8);
  const float4* q = (const float4*)(oe + j * 8);
  float4 a0 = p[0], a1 = p[1], b0 = q[0], b1 = q[1];
  float s = a0.x * b0.x + a0.y * b0.y + a0.z * b0.z + a0.w * b0.w
          + a1.x * b1.x + a1.y * b1.y + a1.z * b1.z + a1.w * b1.w;
  s += __shfl_xor(s, 1); s += __shfl_xor(s, 2);
  s += __shfl_xor(s, 4); s += __shfl_xor(s, 8);
  if (j == 0) alpha[r] = s;
}

// Pack W_hh f32 [1536][512] -> bf16 B_packed[(g*64+cb)*512 + n][8]
// element j of octet = W_hh[g*512+n][cb*8+j]
__global__ void k_wpack(const float* __restrict__ whh, short* __restrict__ bp) {
  int o = blockIdx.x * 256 + threadIdx.x;  // < 98304
  int n = o & 511;
  int gk = o >> 9;           // g*64+cb, 0..191
  int g = gk >> 6, cb = gk & 63;
  const float* src = whh + ((size_t)(g * 512 + n)) * 512 + cb * 8;
  float4 f0 = *(const float4*)src;
  float4 f1 = *(const float4*)(src + 4);
  bh8 w;
  w[0] = f2b(f0.x); w[1] = f2b(f0.y); w[2] = f2b(f0.z); w[3] = f2b(f0.w);
  w[4] = f2b(f1.x); w[5] = f2b(f1.y); w[6] = f2b(f1.z); w[7] = f2b(f1.w);
  *(bh8*)(bp + (size_t)o * 8) = w;
}

// gix[j] = dot(W_ih[j,:], concat(ex_e, s)) ; one wave per output. Also zero hkp.
__global__ void k_gix(const float* __restrict__ wih, const float* __restrict__ exe,
                      const float* __restrict__ sv, float* __restrict__ gix,
                      float* __restrict__ hkp) {
  int t = threadIdx.x;
  if (blockIdx.x < 2) {
    int g = blockIdx.x * 256 + t;
    hkp[g] = 0.f;
  }
  int w = blockIdx.x * 4 + (t >> 6);
  int lane = t & 63;
  float s1 = sv[0];
  float sum = 0.f;
  for (int d = lane; d < DIN; d += 64) {
    float xv = (d < 512) ? exe[d] : s1;
    sum += wih[(size_t)w * DIN + d] * xv;
  }
  sum += __shfl_xor(sum, 1); sum += __shfl_xor(sum, 2);
  sum += __shfl_xor(sum, 4); sum += __shfl_xor(sum, 8);
  sum += __shfl_xor(sum, 16); sum += __shfl_xor(sum, 32);
  if (lane == 0) gix[w] = sum;
}

// single-block softmax over alpha[50000] -> beta
__global__ void k_softmax(const float* __restrict__ alpha, float* __restrict__ beta) {
  __shared__ float red[16];
  __shared__ float stat[2];
  int t = threadIdx.x;  // 1024
  float m = -1e30f;
  for (int i = t; i < KK; i += 1024) m = fmaxf(m, alpha[i]);
  for (int o = 1; o < 64; o <<= 1) m = fmaxf(m, __shfl_xor(m, o));
  if ((t & 63) == 0) red[t >> 6] = m;
  __syncthreads();
  if (t == 0) {
    float mm = red[0];
    for (int i = 1; i < 16; ++i) mm = fmaxf(mm, red[i]);
    stat[0] = mm;
  }
  __syncthreads();
  float Mx = stat[0];
  float ss = 0.f;
  for (int i = t; i < KK; i += 1024) ss += __expf(alpha[i] - Mx);
  for (int o = 1; o < 64; o <<= 1) ss += __shfl_xor(ss, o);
  if ((t & 63) == 0) red[t >> 6] = ss;
  __syncthreads();
  if (t == 0) {
    float tot = 0.f;
    for (int i = 0; i < 16; ++i) tot += red[i];
    stat[1] = tot;
  }
  __syncthreads();
  float inv = 1.f / stat[1];
  for (int i = t; i < KK; i += 1024) beta[i] = __expf(alpha[i] - Mx) * inv;
}

// Fused GEMM+GRU. BM=128 rows/block, 512 thr (8 waves = 4m x 2n), wave tile
// 32r x 32c x 3 gates, mfma_f32_32x32x16_bf16 (32 cy/SIMD each).
// A panel (h->bf16) full-K in LDS: [k-octet 0..63][row 0..127][8], slab stride
// 1026 shorts (2052 B -> staging write is conflict-free).
// B double-buffered 12 KB chunks [3 gates][K32 = 4 octets][64 cols], staged by
// waves 0-5 (2 x global_load_lds 16B each) with COUNTED s_waitcnt vmcnt(2):
// next chunk stays in flight across the phase. 6 MFMA/wave/phase = 384 cy/SIMD
// covers the 12 KB stage (214 cy @ 56 B/cy L2) and its ~400 cy latency.
__global__ __launch_bounds__(512, 2) void k_gemm(
    const float* __restrict__ h, const float* __restrict__ beta,
    const float* __restrict__ gix, const float* __restrict__ b_ih,
    const float* __restrict__ b_hh, const short* __restrict__ bp,
    float* __restrict__ hkp, float* __restrict__ out) {
  __shared__ short Abuf[64 * 1026];   // 131,328 B
  __shared__ short Bbuf[2][6144];     //  24,576 B
  __shared__ float Lbeta[128];        //     512 B
  float* hk = (float*)&Bbuf[0][0];    // 2 KB overlay, used only pre-loop

  const int t = threadIdx.x;
  const int r0 = blockIdx.x * 128;
  const int kb = t & 63;   // K-octet
  const int wid = t >> 6;  // wave id 0..7
  hk[t] = 0.f;

  // ---- Stage A (h -> bf16 LDS) + beta-weighted partials for hkp ----
  float hp[8] = {0.f, 0.f, 0.f, 0.f, 0.f, 0.f, 0.f, 0.f};
  #pragma unroll 2
  for (int pass = 0; pass < 16; ++pass) {
    const int r = pass * 8 + wid;
    const int gr = r0 + r;
    float v[8];
    float bv = 0.f;
    if (gr < KK) {
      const float4* p = (const float4*)(h + (size_t)gr * HH + kb * 8);
      float4 x0 = p[0], x1 = p[1];
      v[0] = x0.x; v[1] = x0.y; v[2] = x0.z; v[3] = x0.w;
      v[4] = x1.x; v[5] = x1.y; v[6] = x1.z; v[7] = x1.w;
      bv = beta[gr];
    } else {
      #pragma unroll
      for (int j = 0; j < 8; ++j) v[j] = 0.f;
    }
    if (kb == 0) Lbeta[r] = bv;
    bh8 w;
    #pragma unroll
    for (int j = 0; j < 8; ++j) { hp[j] += bv * v[j]; w[j] = f2b(v[j]); }
    *(bh8*)&Abuf[kb * 1026 + r * 8] = w;
  }
  __syncthreads();
  #pragma unroll
  for (int j = 0; j < 8; ++j) atomicAdd(&hk[kb * 8 + j], hp[j]);
  __syncthreads();
  atomicAdd(&hkp[t], hk[t]);
  __syncthreads();  // all hk reads done before B staging overwrites Bbuf[0]

  // ---- Main loop ----
  const int lane = t & 63;
  const int l31 = lane & 31;
  const int lh = lane >> 5;
  const int wm = wid & 3;   // 0..3 (row tile)
  const int wn = wid >> 2;  // 0..1 (col tile)
  float* out1 = out + 1;

  // stage chunk (ni, ph) into Bbuf[buf]: 768 x 16B slots, waves 0-5, 2 each
  auto STAGE = [&](int ni, int ph, int buf) {
    if (t < 384) {
      #pragma unroll
      for (int half = 0; half < 2; ++half) {
        const int slot = t + half * 384;
        const int g = slot >> 8, rem = slot & 255;
        const int oo = rem >> 6, c = rem & 63;
        const short* src = bp + (((size_t)(g * 64 + ph * 4 + oo)) * 512 + ni * 64 + c) * 8;
        __builtin_amdgcn_global_load_lds(
            (const __attribute__((address_space(1))) void*)src,
            (__attribute__((address_space(3))) void*)&Bbuf[buf][slot * 8], 16, 0, 0);
      }
    }
  };

  STAGE(0, 0, 0);

  const int arow = (wm * 32 + l31) * 8;
  const int bcol = (wn * 32 + l31) * 8;

  for (int ni = 0; ni < 8; ++ni) {
    fx16 acc0, acc1, acc2;
    #pragma unroll
    for (int q = 0; q < 16; ++q) { acc0[q] = 0.f; acc1[q] = 0.f; acc2[q] = 0.f; }

    #pragma unroll
    for (int ph = 0; ph < 16; ++ph) {
      const int buf = ph & 1;
      if (ph < 15) {
        STAGE(ni, ph + 1, (ph + 1) & 1);
        asm volatile("s_waitcnt vmcnt(2)" ::: "memory");
      } else {
        if (ni < 7) {
          STAGE(ni + 1, 0, 0);
          asm volatile("s_waitcnt vmcnt(2)" ::: "memory");
        } else {
          asm volatile("s_waitcnt vmcnt(0)" ::: "memory");
        }
      }
      __syncthreads();
      #pragma unroll
      for (int kcl = 0; kcl < 2; ++kcl) {
        bh8 a  = *(const bh8*)&Abuf[(ph * 4 + 2 * kcl + lh) * 1026 + arow];
        bh8 br = *(const bh8*)&Bbuf[buf][(2 * kcl + lh) * 512 + bcol];
        bh8 bz = *(const bh8*)&Bbuf[buf][2048 + (2 * kcl + lh) * 512 + bcol];
        bh8 bn = *(const bh8*)&Bbuf[buf][4096 + (2 * kcl + lh) * 512 + bcol];
        acc0 = __builtin_amdgcn_mfma_f32_32x32x16_bf16(a, br, acc0, 0, 0, 0);
        acc1 = __builtin_amdgcn_mfma_f32_32x32x16_bf16(a, bz, acc1, 0, 0, 0);
        acc2 = __builtin_amdgcn_mfma_f32_32x32x16_bf16(a, bn, acc2, 0, 0, 0);
      }
      __syncthreads();
    }

    // ---- epilogue for this 64-col group ----
    const int col = ni * 64 + wn * 32 + l31;
    const int cb = col >> 3, c7 = col & 7;
    const float gxr = gix[col], gxz = gix[col + 512], gxn = gix[col + 1024];
    const float bir = b_ih[col], biz = b_ih[col + 512], bin = b_ih[col + 1024];
    const float bhr = b_hh[col], bhz = b_hh[col + 512], bhn = b_hh[col + 1024];
    const int lrb = wm * 32 + 4 * lh;
    #pragma unroll
    for (int q = 0; q < 16; ++q) {
      const int lr = lrb + (q & 3) + 8 * (q >> 2);
      const int gr = r0 + lr;
      if (gr < KK) {
        const float bv = Lbeta[lr];
        const float rv = sigm(acc0[q] + bv * gxr + bir + bhr);
        const float zv = sigm(acc1[q] + bv * gxz + biz + bhz);
        const float nv = tanh_(bv * gxn + bin + rv * (acc2[q] + bhn));
        const float ho = b2f(Abuf[cb * 1026 + lr * 8 + c7]);
        out1[(size_t)gr * HH + col] = (1.f - zv) * nv + zv * ho;
      }
    }
  }
}

// predict_score = score_W[0:512].ex_e + score_W[512:1024].hkp + score_b
__global__ void k_score(const float* __restrict__ sw, const float* __restrict__ sb,
                        const float* __restrict__ exe, const float* __restrict__ hkp,
                        float* __restrict__ out) {
  __shared__ float red[8];
  int t = threadIdx.x;  // 512
  float v = sw[t] * exe[t] + sw[512 + t] * hkp[t];
  for (int o = 1; o < 64; o <<= 1) v += __shfl_xor(v, o);
  if ((t & 63) == 0) red[t >> 6] = v;
  __syncthreads();
  if (t == 0) {
    float s = sb[0];
    for (int i = 0; i < 8; ++i) s += red[i];
    out[0] = s;
  }
}

extern "C" void kernel_launch(void* const* d_in, const int* in_sizes, int n_in,
                              void* d_out, int out_size, void* d_ws, size_t ws_size,
                              hipStream_t stream) {
  const float* o_e  = (const float*)d_in[0];
  const float* ex_e = (const float*)d_in[1];
  const float* s    = (const float*)d_in[2];
  const float* h    = (const float*)d_in[3];
  const float* km   = (const float*)d_in[4];
  const float* W_ih = (const float*)d_in[5];
  const float* W_hh = (const float*)d_in[6];
  const float* b_ih = (const float*)d_in[7];
  const float* b_hh = (const float*)d_in[8];
  const float* sW   = (const float*)d_in[9];
  const float* sb   = (const float*)d_in[10];
  float* out = (float*)d_out;

  float* wsf   = (float*)d_ws;
  float* alpha = wsf;            // 50000
  float* beta  = wsf + 50048;    // 50000
  float* gix   = wsf + 100096;   // 1536
  float* hkp   = wsf + 101632;   // 512
  short* bp    = (short*)(wsf + 102400);  // 1,572,864 B

  k_alpha<<<3125, 256, 0, stream>>>(km, o_e, alpha);
  k_wpack<<<384, 256, 0, stream>>>(W_hh, bp);
  k_gix<<<384, 256, 0, stream>>>(W_ih, ex_e, s, gix, hkp);
  k_softmax<<<1, 1024, 0, stream>>>(alpha, beta);
  k_gemm<<<391, 512, 0, stream>>>(h, beta, gix, b_ih, b_hh, bp, hkp, out);
  k_score<<<1, 512, 0, stream>>>(sW, sb, ex_e, hkp, out);
}

// Round 6
// 318.654 us; speedup vs baseline: 1.1192x; 1.1192x over previous
//
#include <hip/hip_runtime.h>

#define KK 50000
#define EE 128
#define HH 512
#define DIN 513

typedef short bh8 __attribute__((ext_vector_type(8)));
typedef float fx16 __attribute__((ext_vector_type(16)));

__device__ __forceinline__ short f2b(float f) {
  unsigned u = __float_as_uint(f);
  u = u + 0x7fffu + ((u >> 16) & 1u);
  return (short)(u >> 16);
}
__device__ __forceinline__ float b2f(short b) {
  return __uint_as_float(((unsigned)(unsigned short)b) << 16);
}
__device__ __forceinline__ float sigm(float x) { return 1.f / (1.f + __expf(-x)); }
__device__ __forceinline__ float tanh_(float x) {
  float ax = fabsf(x);
  float e = __expf(-2.f * ax);
  float t = (1.f - e) / (1.f + e);
  return copysignf(t, x);
}

// alpha[r] = dot(km[r,:], o_e) ; 16 lanes per row, 8 f32 each
__global__ void k_alpha(const float* __restrict__ km, const float* __restrict__ oe,
                        float* __restrict__ alpha) {
  int t = blockIdx.x * 256 + threadIdx.x;
  int r = t >> 4, j = t & 15;
  if (r >= KK) return;
  const float4* p = (const float4*)(km + (size_t)r * EE + j * 8);
  const float4* q = (const float4*)(oe + j * 8);
  float4 a0 = p[0], a1 = p[1], b0 = q[0], b1 = q[1];
  float s = a0.x * b0.x + a0.y * b0.y + a0.z * b0.z + a0.w * b0.w
          + a1.x * b1.x + a1.y * b1.y + a1.z * b1.z + a1.w * b1.w;
  s += __shfl_xor(s, 1); s += __shfl_xor(s, 2);
  s += __shfl_xor(s, 4); s += __shfl_xor(s, 8);
  if (j == 0) alpha[r] = s;
}

// Pack W_hh f32 [1536][512] -> bf16 B_packed[(g*64+cb)*512 + n][8]
// element j of octet = W_hh[g*512+n][cb*8+j]
__global__ void k_wpack(const float* __restrict__ whh, short* __restrict__ bp) {
  int o = blockIdx.x * 256 + threadIdx.x;  // < 98304
  int n = o & 511;
  int gk = o >> 9;           // g*64+cb, 0..191
  int g = gk >> 6, cb = gk & 63;
  const float* src = whh + ((size_t)(g * 512 + n)) * 512 + cb * 8;
  float4 f0 = *(const float4*)src;
  float4 f1 = *(const float4*)(src + 4);
  bh8 w;
  w[0] = f2b(f0.x); w[1] = f2b(f0.y); w[2] = f2b(f0.z); w[3] = f2b(f0.w);
  w[4] = f2b(f1.x); w[5] = f2b(f1.y); w[6] = f2b(f1.z); w[7] = f2b(f1.w);
  *(bh8*)(bp + (size_t)o * 8) = w;
}

// gix[j] = dot(W_ih[j,:], concat(ex_e, s)) ; one wave per output. Also zero hkp.
__global__ void k_gix(const float* __restrict__ wih, const float* __restrict__ exe,
                      const float* __restrict__ sv, float* __restrict__ gix,
                      float* __restrict__ hkp) {
  int t = threadIdx.x;
  if (blockIdx.x < 2) {
    int g = blockIdx.x * 256 + t;
    hkp[g] = 0.f;
  }
  int w = blockIdx.x * 4 + (t >> 6);
  int lane = t & 63;
  float s1 = sv[0];
  float sum = 0.f;
  for (int d = lane; d < DIN; d += 64) {
    float xv = (d < 512) ? exe[d] : s1;
    sum += wih[(size_t)w * DIN + d] * xv;
  }
  sum += __shfl_xor(sum, 1); sum += __shfl_xor(sum, 2);
  sum += __shfl_xor(sum, 4); sum += __shfl_xor(sum, 8);
  sum += __shfl_xor(sum, 16); sum += __shfl_xor(sum, 32);
  if (lane == 0) gix[w] = sum;
}

// single-block softmax over alpha[50000] -> beta
__global__ void k_softmax(const float* __restrict__ alpha, float* __restrict__ beta) {
  __shared__ float red[16];
  __shared__ float stat[2];
  int t = threadIdx.x;  // 1024
  float m = -1e30f;
  for (int i = t; i < KK; i += 1024) m = fmaxf(m, alpha[i]);
  for (int o = 1; o < 64; o <<= 1) m = fmaxf(m, __shfl_xor(m, o));
  if ((t & 63) == 0) red[t >> 6] = m;
  __syncthreads();
  if (t == 0) {
    float mm = red[0];
    for (int i = 1; i < 16; ++i) mm = fmaxf(mm, red[i]);
    stat[0] = mm;
  }
  __syncthreads();
  float Mx = stat[0];
  float ss = 0.f;
  for (int i = t; i < KK; i += 1024) ss += __expf(alpha[i] - Mx);
  for (int o = 1; o < 64; o <<= 1) ss += __shfl_xor(ss, o);
  if ((t & 63) == 0) red[t >> 6] = ss;
  __syncthreads();
  if (t == 0) {
    float tot = 0.f;
    for (int i = 0; i < 16; ++i) tot += red[i];
    stat[1] = tot;
  }
  __syncthreads();
  float inv = 1.f / stat[1];
  for (int i = t; i < KK; i += 1024) beta[i] = __expf(alpha[i] - Mx) * inv;
}

// Fused GEMM+GRU. BM=128 rows/block, 512 thr (8 waves = 4m x 2n), wave tile
// 32r x 32c x 3 gates, mfma_f32_32x32x16_bf16 (32 cy/SIMD each).
// A panel (h->bf16) full-K resident in LDS: [k-octet 0..63][row 0..127][8],
// slab stride 1040 shorts.
// B double-buffered 12 KB chunks [3 gates][4 K-octets][64 cols], staged by
// waves 0-5 via global_load_lds(16B) with counted s_waitcnt vmcnt(2) and RAW
// s_barrier (no compiler vmcnt(0) drain). 128 phases = 8 col-groups x 16 K32.
// 6 MFMA/wave/phase = 384 cy/SIMD covers the 12 KB stage from L2.
__global__ __launch_bounds__(512, 2) void k_gemm(
    const float* __restrict__ h, const float* __restrict__ beta,
    const float* __restrict__ gix, const float* __restrict__ b_ih,
    const float* __restrict__ b_hh, const short* __restrict__ bp,
    float* __restrict__ hkp, float* __restrict__ out) {
  __shared__ short Abuf[64 * 1040];   // 133,120 B
  __shared__ short Bbuf[2][6144];     //  24,576 B
  __shared__ float Lbeta[128];        //     512 B
  float* hk = (float*)&Bbuf[0][0];    // 2 KB overlay, used only pre-loop

  const int t = threadIdx.x;
  const int r0 = blockIdx.x * 128;
  const int kb = t & 63;   // K-octet
  const int wid = t >> 6;  // wave id 0..7
  hk[t] = 0.f;

  // ---- Stage A (h -> bf16 LDS) + beta-weighted partials for hkp ----
  float hp[8] = {0.f, 0.f, 0.f, 0.f, 0.f, 0.f, 0.f, 0.f};
  #pragma unroll 2
  for (int pass = 0; pass < 16; ++pass) {
    const int r = pass * 8 + wid;
    const int gr = r0 + r;
    float v[8];
    float bv = 0.f;
    if (gr < KK) {
      const float4* p = (const float4*)(h + (size_t)gr * HH + kb * 8);
      float4 x0 = p[0], x1 = p[1];
      v[0] = x0.x; v[1] = x0.y; v[2] = x0.z; v[3] = x0.w;
      v[4] = x1.x; v[5] = x1.y; v[6] = x1.z; v[7] = x1.w;
      bv = beta[gr];
    } else {
      #pragma unroll
      for (int j = 0; j < 8; ++j) v[j] = 0.f;
    }
    if (kb == 0) Lbeta[r] = bv;
    bh8 w;
    #pragma unroll
    for (int j = 0; j < 8; ++j) { hp[j] += bv * v[j]; w[j] = f2b(v[j]); }
    *(bh8*)&Abuf[kb * 1040 + r * 8] = w;
  }
  __syncthreads();
  #pragma unroll
  for (int j = 0; j < 8; ++j) atomicAdd(&hk[kb * 8 + j], hp[j]);
  __syncthreads();
  atomicAdd(&hkp[t], hk[t]);
  __syncthreads();  // all hk reads done before B staging overwrites Bbuf[0]

  // ---- Main loop: 128 phases (ni 0..7 col-groups x ph 0..15 K32-chunks) ----
  const int lane = t & 63;
  const int l31 = lane & 31;
  const int lh = lane >> 5;
  const int wm = wid >> 1;  // 0..3 (row tile, 32 rows)
  const int wn = wid & 1;   // 0..1 (col tile, 32 cols)
  float* out1 = out + 1;

  // stage chunk (ni, ph) into Bbuf[buf]: 768 x 16B slots, waves 0-5, 2 each
  auto STAGE = [&](int ni, int ph, int buf) {
    if (t < 384) {
      #pragma unroll
      for (int half = 0; half < 2; ++half) {
        const int slot = t + half * 384;
        const int g = slot >> 8, rem = slot & 255;
        const int oo = rem >> 6, c = rem & 63;
        const short* src = bp + (((size_t)(g * 64 + ph * 4 + oo)) * 512 + ni * 64 + c) * 8;
        __builtin_amdgcn_global_load_lds(
            (const __attribute__((address_space(1))) void*)src,
            (__attribute__((address_space(3))) void*)&Bbuf[buf][slot * 8], 16, 0, 0);
      }
    }
  };

  STAGE(0, 0, 0);

  const int arow = (wm * 32 + l31) * 8;
  const int bcol = (wn * 32 + l31) * 8;

  fx16 acc0, acc1, acc2;

  for (int p = 0; p < 128; ++p) {
    const int buf = p & 1;
    const int ph = p & 15;
    const int ni = p >> 4;
    if (ph == 0) {
      #pragma unroll
      for (int q = 0; q < 16; ++q) { acc0[q] = 0.f; acc1[q] = 0.f; acc2[q] = 0.f; }
    }
    // issue next chunk, then wait (counted) for the current chunk's loads
    if (p < 127) {
      const int pn = p + 1;
      STAGE(pn >> 4, pn & 15, pn & 1);
      asm volatile("s_waitcnt vmcnt(2)" ::: "memory");
    } else {
      asm volatile("s_waitcnt vmcnt(0)" ::: "memory");
    }
    asm volatile("s_barrier" ::: "memory");  // raw: no compiler drain

    __builtin_amdgcn_s_setprio(1);
    #pragma unroll
    for (int kcl = 0; kcl < 2; ++kcl) {
      bh8 a = *(const bh8*)&Abuf[(ph * 4 + 2 * kcl + lh) * 1040 + arow];
      const int boff = (2 * kcl + lh) * 512 + bcol;
      bh8 br = *(const bh8*)&Bbuf[buf][boff];
      bh8 bz = *(const bh8*)&Bbuf[buf][boff + 2048];
      bh8 bn = *(const bh8*)&Bbuf[buf][boff + 4096];
      acc0 = __builtin_amdgcn_mfma_f32_32x32x16_bf16(a, br, acc0, 0, 0, 0);
      acc1 = __builtin_amdgcn_mfma_f32_32x32x16_bf16(a, bz, acc1, 0, 0, 0);
      acc2 = __builtin_amdgcn_mfma_f32_32x32x16_bf16(a, bn, acc2, 0, 0, 0);
    }
    __builtin_amdgcn_s_setprio(0);

    if (ph == 15) {
      // ---- epilogue for this 64-col group ----
      const int col = ni * 64 + wn * 32 + l31;
      const int cb = col >> 3, c7 = col & 7;
      const float gxr = gix[col], gxz = gix[col + 512], gxn = gix[col + 1024];
      const float bir = b_ih[col], biz = b_ih[col + 512], bin = b_ih[col + 1024];
      const float bhr = b_hh[col], bhz = b_hh[col + 512], bhn = b_hh[col + 1024];
      const int lrb = wm * 32 + 4 * lh;
      #pragma unroll
      for (int q = 0; q < 16; ++q) {
        const int lr = lrb + (q & 3) + 8 * (q >> 2);
        const int gr = r0 + lr;
        if (gr < KK) {
          const float bv = Lbeta[lr];
          const float rv = sigm(acc0[q] + bv * gxr + bir + bhr);
          const float zv = sigm(acc1[q] + bv * gxz + biz + bhz);
          const float nv = tanh_(bv * gxn + bin + rv * (acc2[q] + bhn));
          const float ho = b2f(Abuf[cb * 1040 + lr * 8 + c7]);
          out1[(size_t)gr * HH + col] = (1.f - zv) * nv + zv * ho;
        }
      }
    }

    asm volatile("s_barrier" ::: "memory");  // reads of buf done before overwrite
  }
}

// predict_score = score_W[0:512].ex_e + score_W[512:1024].hkp + score_b
__global__ void k_score(const float* __restrict__ sw, const float* __restrict__ sb,
                        const float* __restrict__ exe, const float* __restrict__ hkp,
                        float* __restrict__ out) {
  __shared__ float red[8];
  int t = threadIdx.x;  // 512
  float v = sw[t] * exe[t] + sw[512 + t] * hkp[t];
  for (int o = 1; o < 64; o <<= 1) v += __shfl_xor(v, o);
  if ((t & 63) == 0) red[t >> 6] = v;
  __syncthreads();
  if (t == 0) {
    float s = sb[0];
    for (int i = 0; i < 8; ++i) s += red[i];
    out[0] = s;
  }
}

extern "C" void kernel_launch(void* const* d_in, const int* in_sizes, int n_in,
                              void* d_out, int out_size, void* d_ws, size_t ws_size,
                              hipStream_t stream) {
  const float* o_e  = (const float*)d_in[0];
  const float* ex_e = (const float*)d_in[1];
  const float* s    = (const float*)d_in[2];
  const float* h    = (const float*)d_in[3];
  const float* km   = (const float*)d_in[4];
  const float* W_ih = (const float*)d_in[5];
  const float* W_hh = (const float*)d_in[6];
  const float* b_ih = (const float*)d_in[7];
  const float* b_hh = (const float*)d_in[8];
  const float* sW   = (const float*)d_in[9];
  const float* sb   = (const float*)d_in[10];
  float* out = (float*)d_out;

  float* wsf   = (float*)d_ws;
  float* alpha = wsf;            // 50000
  float* beta  = wsf + 50048;    // 50000
  float* gix   = wsf + 100096;   // 1536
  float* hkp   = wsf + 101632;   // 512
  short* bp    = (short*)(wsf + 102400);  // 1,572,864 B

  k_alpha<<<3125, 256, 0, stream>>>(km, o_e, alpha);
  k_wpack<<<384, 256, 0, stream>>>(W_hh, bp);
  k_gix<<<384, 256, 0, stream>>>(W_ih, ex_e, s, gix, hkp);
  k_softmax<<<1, 1024, 0, stream>>>(alpha, beta);
  k_gemm<<<391, 512, 0, stream>>>(h, beta, gix, b_ih, b_hh, bp, hkp, out);
  k_score<<<1, 512, 0, stream>>>(sW, sb, ex_e, hkp, out);
}

// Round 7
// 278.330 us; speedup vs baseline: 1.2814x; 1.1449x over previous
//
#include <hip/hip_runtime.h>

#define KK 50000
#define EE 128
#define HH 512
#define DIN 513

typedef short bh8 __attribute__((ext_vector_type(8)));
typedef float fx16 __attribute__((ext_vector_type(16)));

__device__ __forceinline__ short f2b(float f) {
  unsigned u = __float_as_uint(f);
  u = u + 0x7fffu + ((u >> 16) & 1u);
  return (short)(u >> 16);
}
__device__ __forceinline__ float b2f(short b) {
  return __uint_as_float(((unsigned)(unsigned short)b) << 16);
}
__device__ __forceinline__ float sigm(float x) { return 1.f / (1.f + __expf(-x)); }
__device__ __forceinline__ float tanh_(float x) {
  float ax = fabsf(x);
  float e = __expf(-2.f * ax);
  float t = (1.f - e) / (1.f + e);
  return copysignf(t, x);
}

// alpha[r] = dot(km[r,:], o_e) ; 16 lanes per row, 8 f32 each
__global__ void k_alpha(const float* __restrict__ km, const float* __restrict__ oe,
                        float* __restrict__ alpha) {
  int t = blockIdx.x * 256 + threadIdx.x;
  int r = t >> 4, j = t & 15;
  if (r >= KK) return;
  const float4* p = (const float4*)(km + (size_t)r * EE + j * 8);
  const float4* q = (const float4*)(oe + j * 8);
  float4 a0 = p[0], a1 = p[1], b0 = q[0], b1 = q[1];
  float s = a0.x * b0.x + a0.y * b0.y + a0.z * b0.z + a0.w * b0.w
          + a1.x * b1.x + a1.y * b1.y + a1.z * b1.z + a1.w * b1.w;
  s += __shfl_xor(s, 1); s += __shfl_xor(s, 2);
  s += __shfl_xor(s, 4); s += __shfl_xor(s, 8);
  if (j == 0) alpha[r] = s;
}

// Pack W_hh f32 [1536][512] -> bf16 B_packed[(g*64+cb)*512 + n][8]
// element j of octet = W_hh[g*512+n][cb*8+j]
__global__ void k_wpack(const float* __restrict__ whh, short* __restrict__ bp) {
  int o = blockIdx.x * 256 + threadIdx.x;  // < 98304
  int n = o & 511;
  int gk = o >> 9;           // g*64+cb, 0..191
  int g = gk >> 6, cb = gk & 63;
  const float* src = whh + ((size_t)(g * 512 + n)) * 512 + cb * 8;
  float4 f0 = *(const float4*)src;
  float4 f1 = *(const float4*)(src + 4);
  bh8 w;
  w[0] = f2b(f0.x); w[1] = f2b(f0.y); w[2] = f2b(f0.z); w[3] = f2b(f0.w);
  w[4] = f2b(f1.x); w[5] = f2b(f1.y); w[6] = f2b(f1.z); w[7] = f2b(f1.w);
  *(bh8*)(bp + (size_t)o * 8) = w;
}

// gix[j] = dot(W_ih[j,:], concat(ex_e, s)) ; one wave per output. Also zero hkp.
__global__ void k_gix(const float* __restrict__ wih, const float* __restrict__ exe,
                      const float* __restrict__ sv, float* __restrict__ gix,
                      float* __restrict__ hkp) {
  int t = threadIdx.x;
  if (blockIdx.x < 2) {
    int g = blockIdx.x * 256 + t;
    hkp[g] = 0.f;
  }
  int w = blockIdx.x * 4 + (t >> 6);
  int lane = t & 63;
  float s1 = sv[0];
  float sum = 0.f;
  for (int d = lane; d < DIN; d += 64) {
    float xv = (d < 512) ? exe[d] : s1;
    sum += wih[(size_t)w * DIN + d] * xv;
  }
  sum += __shfl_xor(sum, 1); sum += __shfl_xor(sum, 2);
  sum += __shfl_xor(sum, 4); sum += __shfl_xor(sum, 8);
  sum += __shfl_xor(sum, 16); sum += __shfl_xor(sum, 32);
  if (lane == 0) gix[w] = sum;
}

// single-block softmax over alpha[50000] -> beta
__global__ void k_softmax(const float* __restrict__ alpha, float* __restrict__ beta) {
  __shared__ float red[16];
  __shared__ float stat[2];
  int t = threadIdx.x;  // 1024
  float m = -1e30f;
  for (int i = t; i < KK; i += 1024) m = fmaxf(m, alpha[i]);
  for (int o = 1; o < 64; o <<= 1) m = fmaxf(m, __shfl_xor(m, o));
  if ((t & 63) == 0) red[t >> 6] = m;
  __syncthreads();
  if (t == 0) {
    float mm = red[0];
    for (int i = 1; i < 16; ++i) mm = fmaxf(mm, red[i]);
    stat[0] = mm;
  }
  __syncthreads();
  float Mx = stat[0];
  float ss = 0.f;
  for (int i = t; i < KK; i += 1024) ss += __expf(alpha[i] - Mx);
  for (int o = 1; o < 64; o <<= 1) ss += __shfl_xor(ss, o);
  if ((t & 63) == 0) red[t >> 6] = ss;
  __syncthreads();
  if (t == 0) {
    float tot = 0.f;
    for (int i = 0; i < 16; ++i) tot += red[i];
    stat[1] = tot;
  }
  __syncthreads();
  float inv = 1.f / stat[1];
  for (int i = t; i < KK; i += 1024) beta[i] = __expf(alpha[i] - Mx) * inv;
}

// Fused GEMM+GRU. BM=128 rows/block, 512 thr (8 waves = 4m x 2n), wave tile
// 32r x 32c x 3 gates, mfma_f32_32x32x16_bf16.
// A panel full-K in LDS: [k-octet 0..63][row 0..127][8], stride 1040 shorts.
// B: 4-buffer ring of 6 KB chunks [3 gates][K16 = 2 octets][64 cols], staged by
// waves 0-5 (1 global_load_lds 16B per thread per chunk), 3 chunks in flight.
// Per phase: vmcnt(2) [in-order retire -> chunk p landed] ; raw s_barrier ;
// STAGE(p+3) ; ds_read + 3 MFMA ; epilogue at ph==31. 256 phases.
// vmcnt(18) on post-epilogue phases (16 stores + 2 loads outstanding).
__global__ __launch_bounds__(512, 2) void k_gemm(
    const float* __restrict__ h, const float* __restrict__ beta,
    const float* __restrict__ gix, const float* __restrict__ b_ih,
    const float* __restrict__ b_hh, const short* __restrict__ bp,
    float* __restrict__ hkp, float* __restrict__ out) {
  __shared__ short Abuf[64 * 1040];   // 133,120 B
  __shared__ short Bbuf[4][3072];     //  24,576 B
  __shared__ float Lbeta[128];        //     512 B
  float* hk = (float*)&Bbuf[0][0];    // 2 KB overlay, used only pre-loop

  const int t = threadIdx.x;
  const int r0 = blockIdx.x * 128;
  const int kb = t & 63;   // K-octet
  const int wid = t >> 6;  // wave id 0..7
  hk[t] = 0.f;

  // ---- Stage A (h -> bf16 LDS) + beta-weighted partials for hkp ----
  float hp[8] = {0.f, 0.f, 0.f, 0.f, 0.f, 0.f, 0.f, 0.f};
  #pragma unroll 2
  for (int pass = 0; pass < 16; ++pass) {
    const int r = pass * 8 + wid;
    const int gr = r0 + r;
    float v[8];
    float bv = 0.f;
    if (gr < KK) {
      const float4* p = (const float4*)(h + (size_t)gr * HH + kb * 8);
      float4 x0 = p[0], x1 = p[1];
      v[0] = x0.x; v[1] = x0.y; v[2] = x0.z; v[3] = x0.w;
      v[4] = x1.x; v[5] = x1.y; v[6] = x1.z; v[7] = x1.w;
      bv = beta[gr];
    } else {
      #pragma unroll
      for (int j = 0; j < 8; ++j) v[j] = 0.f;
    }
    if (kb == 0) Lbeta[r] = bv;
    bh8 w;
    #pragma unroll
    for (int j = 0; j < 8; ++j) { hp[j] += bv * v[j]; w[j] = f2b(v[j]); }
    *(bh8*)&Abuf[kb * 1040 + r * 8] = w;
  }
  __syncthreads();
  #pragma unroll
  for (int j = 0; j < 8; ++j) atomicAdd(&hk[kb * 8 + j], hp[j]);
  __syncthreads();
  atomicAdd(&hkp[t], hk[t]);
  __syncthreads();  // hk reads done before B staging overwrites Bbuf

  // ---- Main loop: 256 phases (ni 0..7 col-groups x ph 0..31 K16-chunks) ----
  const int lane = t & 63;
  const int l31 = lane & 31;
  const int lh = lane >> 5;
  const int wm = wid >> 1;  // 0..3 (row tile, 32 rows)
  const int wn = wid & 1;   // 0..1 (col tile, 32 cols)
  float* out1 = out + 1;

  // stage chunk c (0..255, wraps) into Bbuf[c&3]: 384 x 16B, waves 0-5, 1 each
  auto STAGE = [&](int c) {
    if (t < 384) {
      const int ni = c >> 5, ph = c & 31, buf = c & 3;
      const int g = t >> 7, rem = t & 127;
      const int ko = rem >> 6, cc = rem & 63;
      const short* src = bp + (((size_t)(g * 64 + ph * 2 + ko)) * 512 + ni * 64 + cc) * 8;
      __builtin_amdgcn_global_load_lds(
          (const __attribute__((address_space(1))) void*)src,
          (__attribute__((address_space(3))) void*)&Bbuf[buf][t * 8], 16, 0, 0);
    }
  };

  STAGE(0);
  STAGE(1);
  STAGE(2);

  const int arow = (wm * 32 + l31) * 8;
  const int bcol = (wn * 32 + l31) * 8;

  fx16 acc0, acc1, acc2;

  #define PHASE(P, BUF, SLOT)                                                  \
  {                                                                            \
    const int p_ = (P);                                                        \
    const int ph_ = p_ & 31;                                                   \
    const int ni_ = p_ >> 5;                                                   \
    if ((SLOT) == 0) {                                                         \
      if (ph_ == 0) {                                                          \
        _Pragma("unroll")                                                      \
        for (int q = 0; q < 16; ++q) { acc0[q] = 0.f; acc1[q] = 0.f; acc2[q] = 0.f; } \
        if (p_ > 0) { asm volatile("s_waitcnt vmcnt(18)" ::: "memory"); }      \
        else        { asm volatile("s_waitcnt vmcnt(2)" ::: "memory"); }       \
      } else {                                                                 \
        asm volatile("s_waitcnt vmcnt(2)" ::: "memory");                       \
      }                                                                        \
    } else {                                                                   \
      asm volatile("s_waitcnt vmcnt(2)" ::: "memory");                         \
    }                                                                          \
    asm volatile("s_barrier" ::: "memory");                                    \
    STAGE((p_ + 3) & 255);                                                     \
    __builtin_amdgcn_s_setprio(1);                                             \
    bh8 a = *(const bh8*)&Abuf[(ph_ * 2 + lh) * 1040 + arow];                  \
    const int boff = lh * 512 + bcol;                                          \
    bh8 b0 = *(const bh8*)&Bbuf[(BUF)][boff];                                  \
    bh8 b1 = *(const bh8*)&Bbuf[(BUF)][boff + 1024];                           \
    bh8 b2 = *(const bh8*)&Bbuf[(BUF)][boff + 2048];                           \
    acc0 = __builtin_amdgcn_mfma_f32_32x32x16_bf16(a, b0, acc0, 0, 0, 0);      \
    acc1 = __builtin_amdgcn_mfma_f32_32x32x16_bf16(a, b1, acc1, 0, 0, 0);      \
    acc2 = __builtin_amdgcn_mfma_f32_32x32x16_bf16(a, b2, acc2, 0, 0, 0);      \
    __builtin_amdgcn_s_setprio(0);                                             \
    if (ph_ == 31) {                                                           \
      const int col = ni_ * 64 + wn * 32 + l31;                                \
      const int cb = col >> 3, c7 = col & 7;                                   \
      const float gxr = gix[col], gxz = gix[col + 512], gxn = gix[col + 1024]; \
      const float bir = b_ih[col], biz = b_ih[col + 512], bin = b_ih[col + 1024]; \
      const float bhr = b_hh[col], bhz = b_hh[col + 512], bhn = b_hh[col + 1024]; \
      const int lrb = wm * 32 + 4 * lh;                                        \
      _Pragma("unroll")                                                        \
      for (int q = 0; q < 16; ++q) {                                           \
        const int lr = lrb + (q & 3) + 8 * (q >> 2);                           \
        const int gr = r0 + lr;                                                \
        if (gr < KK) {                                                         \
          const float bv = Lbeta[lr];                                          \
          const float rv = sigm(acc0[q] + bv * gxr + bir + bhr);               \
          const float zv = sigm(acc1[q] + bv * gxz + biz + bhz);               \
          const float nv = tanh_(bv * gxn + bin + rv * (acc2[q] + bhn));       \
          const float ho = b2f(Abuf[cb * 1040 + lr * 8 + c7]);                 \
          out1[(size_t)gr * HH + col] = (1.f - zv) * nv + zv * ho;             \
        }                                                                      \
      }                                                                        \
    }                                                                          \
  }

  for (int po = 0; po < 256; po += 4) {
    PHASE(po + 0, 0, 0)
    PHASE(po + 1, 1, 1)
    PHASE(po + 2, 2, 2)
    PHASE(po + 3, 3, 3)
  }
  #undef PHASE
}

// predict_score = score_W[0:512].ex_e + score_W[512:1024].hkp + score_b
__global__ void k_score(const float* __restrict__ sw, const float* __restrict__ sb,
                        const float* __restrict__ exe, const float* __restrict__ hkp,
                        float* __restrict__ out) {
  __shared__ float red[8];
  int t = threadIdx.x;  // 512
  float v = sw[t] * exe[t] + sw[512 + t] * hkp[t];
  for (int o = 1; o < 64; o <<= 1) v += __shfl_xor(v, o);
  if ((t & 63) == 0) red[t >> 6] = v;
  __syncthreads();
  if (t == 0) {
    float s = sb[0];
    for (int i = 0; i < 8; ++i) s += red[i];
    out[0] = s;
  }
}

extern "C" void kernel_launch(void* const* d_in, const int* in_sizes, int n_in,
                              void* d_out, int out_size, void* d_ws, size_t ws_size,
                              hipStream_t stream) {
  const float* o_e  = (const float*)d_in[0];
  const float* ex_e = (const float*)d_in[1];
  const float* s    = (const float*)d_in[2];
  const float* h    = (const float*)d_in[3];
  const float* km   = (const float*)d_in[4];
  const float* W_ih = (const float*)d_in[5];
  const float* W_hh = (const float*)d_in[6];
  const float* b_ih = (const float*)d_in[7];
  const float* b_hh = (const float*)d_in[8];
  const float* sW   = (const float*)d_in[9];
  const float* sb   = (const float*)d_in[10];
  float* out = (float*)d_out;

  float* wsf   = (float*)d_ws;
  float* alpha = wsf;            // 50000
  float* beta  = wsf + 50048;    // 50000
  float* gix   = wsf + 100096;   // 1536
  float* hkp   = wsf + 101632;   // 512
  short* bp    = (short*)(wsf + 102400);  // 1,572,864 B

  k_alpha<<<3125, 256, 0, stream>>>(km, o_e, alpha);
  k_wpack<<<384, 256, 0, stream>>>(W_hh, bp);
  k_gix<<<384, 256, 0, stream>>>(W_ih, ex_e, s, gix, hkp);
  k_softmax<<<1, 1024, 0, stream>>>(alpha, beta);
  k_gemm<<<391, 512, 0, stream>>>(h, beta, gix, b_ih, b_hh, bp, hkp, out);
  k_score<<<1, 512, 0, stream>>>(sW, sb, ex_e, hkp, out);
}